// Round 4
// baseline (1373.643 us; speedup 1.0000x reference)
//
#include <hip/hip_runtime.h>
#include <math.h>

#define N_NODES 100000
#define N_EDGES 1600000
#define NF 64
#define ORDER 8
#define NBLK 391          // ceil(N_NODES/256)
#define DEG_BINS 64

// ---------------- CSR build (once per launch) ----------------

__global__ __launch_bounds__(256) void zero_ints(int* __restrict__ c, int n) {
  int i = blockIdx.x * 256 + threadIdx.x;
  if (i < n) c[i] = 0;
}

__global__ __launch_bounds__(256) void hist_kernel(const int* __restrict__ dst,
                                                   int* __restrict__ counts) {
  int e = blockIdx.x * 256 + threadIdx.x;
  if (e < N_EDGES) atomicAdd(&counts[dst[e]], 1);
}

// hierarchical scan: (1) per-block reduce
__global__ __launch_bounds__(256) void reduce_counts(const int* __restrict__ counts,
                                                     int* __restrict__ blockSums) {
  int i = blockIdx.x * 256 + threadIdx.x;
  int v = (i < N_NODES) ? counts[i] : 0;
  #pragma unroll
  for (int m = 1; m < 64; m <<= 1) v += __shfl_xor(v, m, 64);
  __shared__ int s[4];
  if ((threadIdx.x & 63) == 0) s[threadIdx.x >> 6] = v;
  __syncthreads();
  if (threadIdx.x == 0) blockSums[blockIdx.x] = s[0] + s[1] + s[2] + s[3];
}

// (2) single small block scans the 391 partials
__global__ __launch_bounds__(512) void scan_partials(const int* __restrict__ blockSums,
                                                     int* __restrict__ blockOffs) {
  __shared__ int s[512];
  int t = threadIdx.x;
  int v = (t < NBLK) ? blockSums[t] : 0;
  s[t] = v;
  __syncthreads();
  for (int off = 1; off < 512; off <<= 1) {
    int u = (t >= off) ? s[t - off] : 0;
    __syncthreads();
    s[t] += u;
    __syncthreads();
  }
  if (t < NBLK) blockOffs[t] = s[t] - v;   // exclusive
}

// (3) per-block local scan + global offset -> row_start, cursor
__global__ __launch_bounds__(256) void scan_blocks(const int* __restrict__ counts,
    const int* __restrict__ blockOffs, int* __restrict__ row_start,
    int* __restrict__ cursor) {
  __shared__ int s[256];
  int t = threadIdx.x;
  int i = blockIdx.x * 256 + t;
  int v = (i < N_NODES) ? counts[i] : 0;
  s[t] = v;
  __syncthreads();
  for (int off = 1; off < 256; off <<= 1) {
    int u = (t >= off) ? s[t - off] : 0;
    __syncthreads();
    s[t] += u;
    __syncthreads();
  }
  int excl = s[t] - v + blockOffs[blockIdx.x];
  if (i < N_NODES) { row_start[i] = excl; cursor[i] = excl; }
  if (i == N_NODES - 1) row_start[N_NODES] = excl + v;
}

__global__ __launch_bounds__(256) void fill_kernel(const int* __restrict__ src,
    const int* __restrict__ dst, const float* __restrict__ ew,
    int* __restrict__ cursor, int2* __restrict__ adj) {
  int e = blockIdx.x * 256 + threadIdx.x;
  if (e >= N_EDGES) return;
  int d = dst[e];
  int pos = atomicAdd(&cursor[d], 1);
  adj[pos] = make_int2(src[e], __float_as_int(ew[e]));
}

// ---------------- degree counting-sort (node permutation) ----------------

__global__ __launch_bounds__(256) void deg_hist(const int* __restrict__ counts,
                                                int* __restrict__ deg_counts) {
  int i = blockIdx.x * 256 + threadIdx.x;
  if (i < N_NODES) atomicAdd(&deg_counts[min(counts[i], DEG_BINS - 1)], 1);
}

__global__ __launch_bounds__(64) void deg_scan(const int* __restrict__ deg_counts,
                                               int* __restrict__ deg_cur) {
  int t = threadIdx.x;
  int orig = deg_counts[t];
  int v = orig;
  #pragma unroll
  for (int off = 1; off < 64; off <<= 1) {
    int u = __shfl_up(v, off, 64);
    if (t >= off) v += u;
  }
  deg_cur[t] = v - orig;   // exclusive
}

__global__ __launch_bounds__(256) void deg_scatter(const int* __restrict__ counts,
    int* __restrict__ deg_cur, int* __restrict__ perm) {
  int i = blockIdx.x * 256 + threadIdx.x;
  if (i >= N_NODES) return;
  int d = min(counts[i], DEG_BINS - 1);
  int pos = atomicAdd(&deg_cur[d], 1);
  perm[pos] = i;
}

// ---------------- propagation ----------------

__global__ __launch_bounds__(256) void init_kernel(const float4* __restrict__ X,
    float4* __restrict__ xc, float4* __restrict__ prop, int n4) {
  int i = blockIdx.x * 256 + threadIdx.x;
  if (i >= n4) return;
  float4 v = X[i];
  v.x *= 0.5f; v.y *= 0.5f; v.z *= 0.5f; v.w *= 0.5f;
  xc[i] = v;
  prop[i] = v;
}

// gather-sum per dst node: 16 lanes/node, float4/lane, degree-sorted order,
// 4-edge unroll with independent accumulators for gather ILP.
__global__ __launch_bounds__(256) void spmm_csr(const float4* __restrict__ x,
    const int* __restrict__ row_start, const int2* __restrict__ adj,
    const int* __restrict__ perm, float4* __restrict__ xn,
    float4* __restrict__ prop) {
  const int g = blockIdx.x * 16 + (threadIdx.x >> 4);
  const int f4 = threadIdx.x & 15;
  if (g >= N_NODES) return;
  const int node = perm[g];
  const int beg = row_start[node];
  const int end = row_start[node + 1];
  float4 a0 = make_float4(0.f, 0.f, 0.f, 0.f);
  float4 a1 = a0, a2 = a0, a3 = a0;
  int p = beg;
  for (; p + 4 <= end; p += 4) {
    int2 e0 = adj[p];
    int2 e1 = adj[p + 1];
    int2 e2 = adj[p + 2];
    int2 e3 = adj[p + 3];
    float4 v0 = x[(size_t)e0.x * 16 + f4];
    float4 v1 = x[(size_t)e1.x * 16 + f4];
    float4 v2 = x[(size_t)e2.x * 16 + f4];
    float4 v3 = x[(size_t)e3.x * 16 + f4];
    float w0 = __int_as_float(e0.y), w1 = __int_as_float(e1.y);
    float w2 = __int_as_float(e2.y), w3 = __int_as_float(e3.y);
    a0.x = fmaf(v0.x, w0, a0.x); a0.y = fmaf(v0.y, w0, a0.y);
    a0.z = fmaf(v0.z, w0, a0.z); a0.w = fmaf(v0.w, w0, a0.w);
    a1.x = fmaf(v1.x, w1, a1.x); a1.y = fmaf(v1.y, w1, a1.y);
    a1.z = fmaf(v1.z, w1, a1.z); a1.w = fmaf(v1.w, w1, a1.w);
    a2.x = fmaf(v2.x, w2, a2.x); a2.y = fmaf(v2.y, w2, a2.y);
    a2.z = fmaf(v2.z, w2, a2.z); a2.w = fmaf(v2.w, w2, a2.w);
    a3.x = fmaf(v3.x, w3, a3.x); a3.y = fmaf(v3.y, w3, a3.y);
    a3.z = fmaf(v3.z, w3, a3.z); a3.w = fmaf(v3.w, w3, a3.w);
  }
  for (; p < end; ++p) {
    int2 e0 = adj[p];
    float4 v0 = x[(size_t)e0.x * 16 + f4];
    float w0 = __int_as_float(e0.y);
    a0.x = fmaf(v0.x, w0, a0.x); a0.y = fmaf(v0.y, w0, a0.y);
    a0.z = fmaf(v0.z, w0, a0.z); a0.w = fmaf(v0.w, w0, a0.w);
  }
  a0.x += a1.x + a2.x + a3.x;
  a0.y += a1.y + a2.y + a3.y;
  a0.z += a1.z + a2.z + a3.z;
  a0.w += a1.w + a2.w + a3.w;
  const size_t o = (size_t)node * 16 + f4;
  xn[o] = a0;
  float4 pr = prop[o];
  pr.x += a0.x; pr.y += a0.y; pr.z += a0.z; pr.w += a0.w;
  prop[o] = pr;
}

// ---------------- fused tail, register-blocked ----------------
__global__ __launch_bounds__(256) void tail_kernel(
    const float* __restrict__ prop, const float* __restrict__ W0,
    const float* __restrict__ b0, const float* __restrict__ W1,
    const float* __restrict__ b1, float* __restrict__ out) {
  __shared__ float sXT[64][33];
  __shared__ float sHT[256][33];
  __shared__ float sPart[32][33];
  __shared__ float sHinv[32];

  const int t = threadIdx.x;
  const int lane = t & 63;
  const int w = t >> 6;
  const int base = blockIdx.x * 32;

  #pragma unroll
  for (int it = 0; it < 8; ++it) {
    const int nb = it * 4 + w;
    float v = prop[(size_t)(base + nb) * NF + lane];
    float ss = v * v;
    #pragma unroll
    for (int m = 1; m < 64; m <<= 1) ss += __shfl_xor(ss, m, 64);
    float nrm = sqrtf(ss) * (1.0f / 9.0f);
    float scale = (1.0f / 9.0f) / (1e-12f + nrm);
    sXT[lane][nb] = v * scale;
  }
  __syncthreads();

  const int tc = t >> 3;
  const int tn = t & 7;
  const float4* W0v = (const float4*)W0;
  float4 b0a = ((const float4*)b0)[2 * tc];
  float4 b0b = ((const float4*)b0)[2 * tc + 1];
  float acc[4][8];
  #pragma unroll
  for (int j = 0; j < 4; ++j) {
    acc[j][0] = b0a.x; acc[j][1] = b0a.y; acc[j][2] = b0a.z; acc[j][3] = b0a.w;
    acc[j][4] = b0b.x; acc[j][5] = b0b.y; acc[j][6] = b0b.z; acc[j][7] = b0b.w;
  }
  #pragma unroll 2
  for (int k = 0; k < NF; ++k) {
    float4 wa = W0v[k * 64 + 2 * tc];
    float4 wb = W0v[k * 64 + 2 * tc + 1];
    float xs0 = sXT[k][tn];
    float xs1 = sXT[k][tn + 8];
    float xs2 = sXT[k][tn + 16];
    float xs3 = sXT[k][tn + 24];
    #pragma unroll
    for (int j = 0; j < 4; ++j) {
      float xs = (j == 0) ? xs0 : (j == 1) ? xs1 : (j == 2) ? xs2 : xs3;
      acc[j][0] = fmaf(xs, wa.x, acc[j][0]);
      acc[j][1] = fmaf(xs, wa.y, acc[j][1]);
      acc[j][2] = fmaf(xs, wa.z, acc[j][2]);
      acc[j][3] = fmaf(xs, wa.w, acc[j][3]);
      acc[j][4] = fmaf(xs, wb.x, acc[j][4]);
      acc[j][5] = fmaf(xs, wb.y, acc[j][5]);
      acc[j][6] = fmaf(xs, wb.z, acc[j][6]);
      acc[j][7] = fmaf(xs, wb.w, acc[j][7]);
    }
  }

  #pragma unroll
  for (int j = 0; j < 4; ++j) {
    float part = 0.0f;
    #pragma unroll
    for (int i = 0; i < 8; ++i) {
      float a = fmaxf(acc[j][i], 0.0f);
      acc[j][i] = a;
      part = fmaf(a, a, part);
    }
    sPart[tn + 8 * j][tc] = part;
  }
  __syncthreads();

  if (t < 32) {
    float s = 0.0f;
    #pragma unroll
    for (int i = 0; i < 32; ++i) s += sPart[t][i];
    sHinv[t] = 1.0f / (1e-12f + sqrtf(s));
  }
  __syncthreads();

  #pragma unroll
  for (int j = 0; j < 4; ++j) {
    float sc = sHinv[tn + 8 * j];
    #pragma unroll
    for (int i = 0; i < 8; ++i)
      sHT[8 * tc + i][tn + 8 * j] = acc[j][i] * sc;
  }
  __syncthreads();

  const int tn2 = t & 15;
  const int tc2 = t >> 4;
  const bool c3 = (tc2 < 15);
  float a00 = b1[tc2],      a01 = b1[tc2 + 16], a02 = c3 ? b1[tc2 + 32] : 0.0f;
  float a10 = a00,          a11 = a01,          a12 = a02;
  #pragma unroll 4
  for (int k = 0; k < 256; ++k) {
    float h0 = sHT[k][tn2];
    float h1 = sHT[k][tn2 + 16];
    float w1a = W1[k * 47 + tc2];
    float w1b = W1[k * 47 + tc2 + 16];
    float w1c = c3 ? W1[k * 47 + tc2 + 32] : 0.0f;
    a00 = fmaf(h0, w1a, a00);
    a01 = fmaf(h0, w1b, a01);
    a02 = fmaf(h0, w1c, a02);
    a10 = fmaf(h1, w1a, a10);
    a11 = fmaf(h1, w1b, a11);
    a12 = fmaf(h1, w1c, a12);
  }
  {
    const size_t n0 = (size_t)(base + tn2) * 47;
    const size_t n1 = (size_t)(base + tn2 + 16) * 47;
    out[n0 + tc2] = a00;
    out[n0 + tc2 + 16] = a01;
    if (c3) out[n0 + tc2 + 32] = a02;
    out[n1 + tc2] = a10;
    out[n1 + tc2 + 16] = a11;
    if (c3) out[n1 + tc2 + 32] = a12;
  }
}

extern "C" void kernel_launch(void* const* d_in, const int* in_sizes, int n_in,
                              void* d_out, int out_size, void* d_ws, size_t ws_size,
                              hipStream_t stream) {
  (void)in_sizes; (void)n_in; (void)out_size; (void)ws_size;
  const float* X   = (const float*)d_in[0];
  const int*   src = (const int*)d_in[1];
  const int*   dst = (const int*)d_in[2];
  const float* ew  = (const float*)d_in[3];
  const float* W0  = (const float*)d_in[4];
  const float* b0  = (const float*)d_in[5];
  const float* W1  = (const float*)d_in[6];
  const float* b1  = (const float*)d_in[7];
  float* out = (float*)d_out;

  const size_t nf = (size_t)N_NODES * NF;
  float* bufA = (float*)d_ws;
  float* bufB = bufA + nf;
  float* prop = bufB + nf;
  int* counts     = (int*)(prop + nf);
  int* row_start  = counts + N_NODES;            // N_NODES+1
  int* cursor     = row_start + (N_NODES + 1);
  int* perm       = cursor + N_NODES;
  int* blockSums  = perm + N_NODES;
  int* blockOffs  = blockSums + NBLK;
  int* deg_counts = blockOffs + NBLK;
  int* deg_cur    = deg_counts + DEG_BINS;
  int2* adj       = (int2*)(((uintptr_t)(deg_cur + DEG_BINS) + 15) & ~(uintptr_t)15);

  const int eblocks = (N_EDGES + 255) / 256;

  zero_ints<<<NBLK, 256, 0, stream>>>(counts, N_NODES);
  zero_ints<<<1, 256, 0, stream>>>(deg_counts, DEG_BINS);
  hist_kernel<<<eblocks, 256, 0, stream>>>(dst, counts);
  reduce_counts<<<NBLK, 256, 0, stream>>>(counts, blockSums);
  scan_partials<<<1, 512, 0, stream>>>(blockSums, blockOffs);
  scan_blocks<<<NBLK, 256, 0, stream>>>(counts, blockOffs, row_start, cursor);
  fill_kernel<<<eblocks, 256, 0, stream>>>(src, dst, ew, cursor, adj);
  deg_hist<<<NBLK, 256, 0, stream>>>(counts, deg_counts);
  deg_scan<<<1, 64, 0, stream>>>(deg_counts, deg_cur);
  deg_scatter<<<NBLK, 256, 0, stream>>>(counts, deg_cur, perm);

  const int n4 = (int)(nf / 4);
  init_kernel<<<(n4 + 255) / 256, 256, 0, stream>>>(
      (const float4*)X, (float4*)bufA, (float4*)prop, n4);

  float* xc = bufA;
  float* xn = bufB;
  for (int r = 0; r < ORDER; ++r) {
    spmm_csr<<<(N_NODES + 15) / 16, 256, 0, stream>>>(
        (const float4*)xc, row_start, adj, perm, (float4*)xn, (float4*)prop);
    float* tmp = xc; xc = xn; xn = tmp;
  }

  tail_kernel<<<N_NODES / 32, 256, 0, stream>>>(prop, W0, b0, W1, b1, out);
}

// Round 5
// 877.231 us; speedup vs baseline: 1.5659x; 1.5659x over previous
//
#include <hip/hip_runtime.h>
#include <math.h>

#define N_NODES 100000
#define N_EDGES 1600000
#define NF 64
#define ORDER 8
#define NBLK 391          // ceil(N_NODES/256)

// ---------------- CSR build (once per launch) ----------------

__global__ __launch_bounds__(256) void zero_ints(int* __restrict__ c, int n) {
  int i = blockIdx.x * 256 + threadIdx.x;
  if (i < n) c[i] = 0;
}

__global__ __launch_bounds__(256) void hist_kernel(const int* __restrict__ dst,
                                                   int* __restrict__ counts) {
  int e = blockIdx.x * 256 + threadIdx.x;
  if (e < N_EDGES) atomicAdd(&counts[dst[e]], 1);
}

// hierarchical scan: (1) per-block reduce
__global__ __launch_bounds__(256) void reduce_counts(const int* __restrict__ counts,
                                                     int* __restrict__ blockSums) {
  int i = blockIdx.x * 256 + threadIdx.x;
  int v = (i < N_NODES) ? counts[i] : 0;
  #pragma unroll
  for (int m = 1; m < 64; m <<= 1) v += __shfl_xor(v, m, 64);
  __shared__ int s[4];
  if ((threadIdx.x & 63) == 0) s[threadIdx.x >> 6] = v;
  __syncthreads();
  if (threadIdx.x == 0) blockSums[blockIdx.x] = s[0] + s[1] + s[2] + s[3];
}

// (2) single small block scans the 391 partials
__global__ __launch_bounds__(512) void scan_partials(const int* __restrict__ blockSums,
                                                     int* __restrict__ blockOffs) {
  __shared__ int s[512];
  int t = threadIdx.x;
  int v = (t < NBLK) ? blockSums[t] : 0;
  s[t] = v;
  __syncthreads();
  for (int off = 1; off < 512; off <<= 1) {
    int u = (t >= off) ? s[t - off] : 0;
    __syncthreads();
    s[t] += u;
    __syncthreads();
  }
  if (t < NBLK) blockOffs[t] = s[t] - v;   // exclusive
}

// (3) per-block local scan + global offset -> row_start, cursor
__global__ __launch_bounds__(256) void scan_blocks(const int* __restrict__ counts,
    const int* __restrict__ blockOffs, int* __restrict__ row_start,
    int* __restrict__ cursor) {
  __shared__ int s[256];
  int t = threadIdx.x;
  int i = blockIdx.x * 256 + t;
  int v = (i < N_NODES) ? counts[i] : 0;
  s[t] = v;
  __syncthreads();
  for (int off = 1; off < 256; off <<= 1) {
    int u = (t >= off) ? s[t - off] : 0;
    __syncthreads();
    s[t] += u;
    __syncthreads();
  }
  int excl = s[t] - v + blockOffs[blockIdx.x];
  if (i < N_NODES) { row_start[i] = excl; cursor[i] = excl; }
  if (i == N_NODES - 1) row_start[N_NODES] = excl + v;
}

__global__ __launch_bounds__(256) void fill_kernel(const int* __restrict__ src,
    const int* __restrict__ dst, const float* __restrict__ ew,
    int* __restrict__ cursor, int2* __restrict__ adj) {
  int e = blockIdx.x * 256 + threadIdx.x;
  if (e >= N_EDGES) return;
  int d = dst[e];
  int pos = atomicAdd(&cursor[d], 1);
  adj[pos] = make_int2(src[e], __float_as_int(ew[e]));
}

// ---------------- propagation ----------------

__global__ __launch_bounds__(256) void init_kernel(const float4* __restrict__ X,
    float4* __restrict__ xc, float4* __restrict__ prop, int n4) {
  int i = blockIdx.x * 256 + threadIdx.x;
  if (i >= n4) return;
  float4 v = X[i];
  v.x *= 0.5f; v.y *= 0.5f; v.z *= 0.5f; v.w *= 0.5f;
  xc[i] = v;
  prop[i] = v;
}

// gather-sum per dst node: 16 lanes/node, float4/lane, natural order,
// 4-edge unroll with independent accumulators for gather ILP.
__global__ __launch_bounds__(256) void spmm_csr(const float4* __restrict__ x,
    const int* __restrict__ row_start, const int2* __restrict__ adj,
    float4* __restrict__ xn, float4* __restrict__ prop) {
  const int node = blockIdx.x * 16 + (threadIdx.x >> 4);
  const int f4 = threadIdx.x & 15;
  if (node >= N_NODES) return;
  const int beg = row_start[node];
  const int end = row_start[node + 1];
  float4 a0 = make_float4(0.f, 0.f, 0.f, 0.f);
  float4 a1 = a0, a2 = a0, a3 = a0;
  int p = beg;
  for (; p + 4 <= end; p += 4) {
    int2 e0 = adj[p];
    int2 e1 = adj[p + 1];
    int2 e2 = adj[p + 2];
    int2 e3 = adj[p + 3];
    float4 v0 = x[(size_t)e0.x * 16 + f4];
    float4 v1 = x[(size_t)e1.x * 16 + f4];
    float4 v2 = x[(size_t)e2.x * 16 + f4];
    float4 v3 = x[(size_t)e3.x * 16 + f4];
    float w0 = __int_as_float(e0.y), w1 = __int_as_float(e1.y);
    float w2 = __int_as_float(e2.y), w3 = __int_as_float(e3.y);
    a0.x = fmaf(v0.x, w0, a0.x); a0.y = fmaf(v0.y, w0, a0.y);
    a0.z = fmaf(v0.z, w0, a0.z); a0.w = fmaf(v0.w, w0, a0.w);
    a1.x = fmaf(v1.x, w1, a1.x); a1.y = fmaf(v1.y, w1, a1.y);
    a1.z = fmaf(v1.z, w1, a1.z); a1.w = fmaf(v1.w, w1, a1.w);
    a2.x = fmaf(v2.x, w2, a2.x); a2.y = fmaf(v2.y, w2, a2.y);
    a2.z = fmaf(v2.z, w2, a2.z); a2.w = fmaf(v2.w, w2, a2.w);
    a3.x = fmaf(v3.x, w3, a3.x); a3.y = fmaf(v3.y, w3, a3.y);
    a3.z = fmaf(v3.z, w3, a3.z); a3.w = fmaf(v3.w, w3, a3.w);
  }
  for (; p < end; ++p) {
    int2 e0 = adj[p];
    float4 v0 = x[(size_t)e0.x * 16 + f4];
    float w0 = __int_as_float(e0.y);
    a0.x = fmaf(v0.x, w0, a0.x); a0.y = fmaf(v0.y, w0, a0.y);
    a0.z = fmaf(v0.z, w0, a0.z); a0.w = fmaf(v0.w, w0, a0.w);
  }
  a0.x += a1.x + a2.x + a3.x;
  a0.y += a1.y + a2.y + a3.y;
  a0.z += a1.z + a2.z + a3.z;
  a0.w += a1.w + a2.w + a3.w;
  const size_t o = (size_t)node * 16 + f4;
  xn[o] = a0;
  float4 pr = prop[o];
  pr.x += a0.x; pr.y += a0.y; pr.z += a0.z; pr.w += a0.w;
  prop[o] = pr;
}

// ---------------- fused tail, register-blocked ----------------
__global__ __launch_bounds__(256) void tail_kernel(
    const float* __restrict__ prop, const float* __restrict__ W0,
    const float* __restrict__ b0, const float* __restrict__ W1,
    const float* __restrict__ b1, float* __restrict__ out) {
  __shared__ float sXT[64][33];
  __shared__ float sHT[256][33];
  __shared__ float sPart[32][33];
  __shared__ float sHinv[32];

  const int t = threadIdx.x;
  const int lane = t & 63;
  const int w = t >> 6;
  const int base = blockIdx.x * 32;

  #pragma unroll
  for (int it = 0; it < 8; ++it) {
    const int nb = it * 4 + w;
    float v = prop[(size_t)(base + nb) * NF + lane];
    float ss = v * v;
    #pragma unroll
    for (int m = 1; m < 64; m <<= 1) ss += __shfl_xor(ss, m, 64);
    float nrm = sqrtf(ss) * (1.0f / 9.0f);
    float scale = (1.0f / 9.0f) / (1e-12f + nrm);
    sXT[lane][nb] = v * scale;
  }
  __syncthreads();

  const int tc = t >> 3;
  const int tn = t & 7;
  const float4* W0v = (const float4*)W0;
  float4 b0a = ((const float4*)b0)[2 * tc];
  float4 b0b = ((const float4*)b0)[2 * tc + 1];
  float acc[4][8];
  #pragma unroll
  for (int j = 0; j < 4; ++j) {
    acc[j][0] = b0a.x; acc[j][1] = b0a.y; acc[j][2] = b0a.z; acc[j][3] = b0a.w;
    acc[j][4] = b0b.x; acc[j][5] = b0b.y; acc[j][6] = b0b.z; acc[j][7] = b0b.w;
  }
  #pragma unroll 2
  for (int k = 0; k < NF; ++k) {
    float4 wa = W0v[k * 64 + 2 * tc];
    float4 wb = W0v[k * 64 + 2 * tc + 1];
    float xs0 = sXT[k][tn];
    float xs1 = sXT[k][tn + 8];
    float xs2 = sXT[k][tn + 16];
    float xs3 = sXT[k][tn + 24];
    #pragma unroll
    for (int j = 0; j < 4; ++j) {
      float xs = (j == 0) ? xs0 : (j == 1) ? xs1 : (j == 2) ? xs2 : xs3;
      acc[j][0] = fmaf(xs, wa.x, acc[j][0]);
      acc[j][1] = fmaf(xs, wa.y, acc[j][1]);
      acc[j][2] = fmaf(xs, wa.z, acc[j][2]);
      acc[j][3] = fmaf(xs, wa.w, acc[j][3]);
      acc[j][4] = fmaf(xs, wb.x, acc[j][4]);
      acc[j][5] = fmaf(xs, wb.y, acc[j][5]);
      acc[j][6] = fmaf(xs, wb.z, acc[j][6]);
      acc[j][7] = fmaf(xs, wb.w, acc[j][7]);
    }
  }

  #pragma unroll
  for (int j = 0; j < 4; ++j) {
    float part = 0.0f;
    #pragma unroll
    for (int i = 0; i < 8; ++i) {
      float a = fmaxf(acc[j][i], 0.0f);
      acc[j][i] = a;
      part = fmaf(a, a, part);
    }
    sPart[tn + 8 * j][tc] = part;
  }
  __syncthreads();

  if (t < 32) {
    float s = 0.0f;
    #pragma unroll
    for (int i = 0; i < 32; ++i) s += sPart[t][i];
    sHinv[t] = 1.0f / (1e-12f + sqrtf(s));
  }
  __syncthreads();

  #pragma unroll
  for (int j = 0; j < 4; ++j) {
    float sc = sHinv[tn + 8 * j];
    #pragma unroll
    for (int i = 0; i < 8; ++i)
      sHT[8 * tc + i][tn + 8 * j] = acc[j][i] * sc;
  }
  __syncthreads();

  const int tn2 = t & 15;
  const int tc2 = t >> 4;
  const bool c3 = (tc2 < 15);
  float a00 = b1[tc2],      a01 = b1[tc2 + 16], a02 = c3 ? b1[tc2 + 32] : 0.0f;
  float a10 = a00,          a11 = a01,          a12 = a02;
  #pragma unroll 4
  for (int k = 0; k < 256; ++k) {
    float h0 = sHT[k][tn2];
    float h1 = sHT[k][tn2 + 16];
    float w1a = W1[k * 47 + tc2];
    float w1b = W1[k * 47 + tc2 + 16];
    float w1c = c3 ? W1[k * 47 + tc2 + 32] : 0.0f;
    a00 = fmaf(h0, w1a, a00);
    a01 = fmaf(h0, w1b, a01);
    a02 = fmaf(h0, w1c, a02);
    a10 = fmaf(h1, w1a, a10);
    a11 = fmaf(h1, w1b, a11);
    a12 = fmaf(h1, w1c, a12);
  }
  {
    const size_t n0 = (size_t)(base + tn2) * 47;
    const size_t n1 = (size_t)(base + tn2 + 16) * 47;
    out[n0 + tc2] = a00;
    out[n0 + tc2 + 16] = a01;
    if (c3) out[n0 + tc2 + 32] = a02;
    out[n1 + tc2] = a10;
    out[n1 + tc2 + 16] = a11;
    if (c3) out[n1 + tc2 + 32] = a12;
  }
}

extern "C" void kernel_launch(void* const* d_in, const int* in_sizes, int n_in,
                              void* d_out, int out_size, void* d_ws, size_t ws_size,
                              hipStream_t stream) {
  (void)in_sizes; (void)n_in; (void)out_size; (void)ws_size;
  const float* X   = (const float*)d_in[0];
  const int*   src = (const int*)d_in[1];
  const int*   dst = (const int*)d_in[2];
  const float* ew  = (const float*)d_in[3];
  const float* W0  = (const float*)d_in[4];
  const float* b0  = (const float*)d_in[5];
  const float* W1  = (const float*)d_in[6];
  const float* b1  = (const float*)d_in[7];
  float* out = (float*)d_out;

  const size_t nf = (size_t)N_NODES * NF;
  float* bufA = (float*)d_ws;
  float* bufB = bufA + nf;
  float* prop = bufB + nf;
  int* counts     = (int*)(prop + nf);
  int* row_start  = counts + N_NODES;            // N_NODES+1
  int* cursor     = row_start + (N_NODES + 1);
  int* blockSums  = cursor + N_NODES;
  int* blockOffs  = blockSums + NBLK;
  int2* adj       = (int2*)(((uintptr_t)(blockOffs + NBLK) + 15) & ~(uintptr_t)15);

  const int eblocks = (N_EDGES + 255) / 256;

  zero_ints<<<NBLK, 256, 0, stream>>>(counts, N_NODES);
  hist_kernel<<<eblocks, 256, 0, stream>>>(dst, counts);
  reduce_counts<<<NBLK, 256, 0, stream>>>(counts, blockSums);
  scan_partials<<<1, 512, 0, stream>>>(blockSums, blockOffs);
  scan_blocks<<<NBLK, 256, 0, stream>>>(counts, blockOffs, row_start, cursor);
  fill_kernel<<<eblocks, 256, 0, stream>>>(src, dst, ew, cursor, adj);

  const int n4 = (int)(nf / 4);
  init_kernel<<<(n4 + 255) / 256, 256, 0, stream>>>(
      (const float4*)X, (float4*)bufA, (float4*)prop, n4);

  float* xc = bufA;
  float* xn = bufB;
  for (int r = 0; r < ORDER; ++r) {
    spmm_csr<<<(N_NODES + 15) / 16, 256, 0, stream>>>(
        (const float4*)xc, row_start, adj, (float4*)xn, (float4*)prop);
    float* tmp = xc; xc = xn; xn = tmp;
  }

  tail_kernel<<<N_NODES / 32, 256, 0, stream>>>(prop, W0, b0, W1, b1, out);
}

// Round 6
// 852.221 us; speedup vs baseline: 1.6118x; 1.0293x over previous
//
#include <hip/hip_runtime.h>
#include <math.h>

#define N_NODES 100000
#define N_EDGES 1600000
#define NF 64
#define ORDER 8
#define NBLK 391          // ceil(N_NODES/256)

// ---------------- CSR build (once per launch) ----------------

__global__ __launch_bounds__(256) void zero_ints(int* __restrict__ c, int n) {
  int i = blockIdx.x * 256 + threadIdx.x;
  if (i < n) c[i] = 0;
}

__global__ __launch_bounds__(256) void hist_kernel(const int* __restrict__ dst,
                                                   int* __restrict__ counts) {
  int e = blockIdx.x * 256 + threadIdx.x;
  if (e < N_EDGES) atomicAdd(&counts[dst[e]], 1);
}

__global__ __launch_bounds__(256) void reduce_counts(const int* __restrict__ counts,
                                                     int* __restrict__ blockSums) {
  int i = blockIdx.x * 256 + threadIdx.x;
  int v = (i < N_NODES) ? counts[i] : 0;
  #pragma unroll
  for (int m = 1; m < 64; m <<= 1) v += __shfl_xor(v, m, 64);
  __shared__ int s[4];
  if ((threadIdx.x & 63) == 0) s[threadIdx.x >> 6] = v;
  __syncthreads();
  if (threadIdx.x == 0) blockSums[blockIdx.x] = s[0] + s[1] + s[2] + s[3];
}

__global__ __launch_bounds__(512) void scan_partials(const int* __restrict__ blockSums,
                                                     int* __restrict__ blockOffs) {
  __shared__ int s[512];
  int t = threadIdx.x;
  int v = (t < NBLK) ? blockSums[t] : 0;
  s[t] = v;
  __syncthreads();
  for (int off = 1; off < 512; off <<= 1) {
    int u = (t >= off) ? s[t - off] : 0;
    __syncthreads();
    s[t] += u;
    __syncthreads();
  }
  if (t < NBLK) blockOffs[t] = s[t] - v;   // exclusive
}

__global__ __launch_bounds__(256) void scan_blocks(const int* __restrict__ counts,
    const int* __restrict__ blockOffs, int* __restrict__ row_start,
    int* __restrict__ cursor) {
  __shared__ int s[256];
  int t = threadIdx.x;
  int i = blockIdx.x * 256 + t;
  int v = (i < N_NODES) ? counts[i] : 0;
  s[t] = v;
  __syncthreads();
  for (int off = 1; off < 256; off <<= 1) {
    int u = (t >= off) ? s[t - off] : 0;
    __syncthreads();
    s[t] += u;
    __syncthreads();
  }
  int excl = s[t] - v + blockOffs[blockIdx.x];
  if (i < N_NODES) { row_start[i] = excl; cursor[i] = excl; }
  if (i == N_NODES - 1) row_start[N_NODES] = excl + v;
}

__global__ __launch_bounds__(256) void fill_kernel(const int* __restrict__ src,
    const int* __restrict__ dst, const float* __restrict__ ew,
    int* __restrict__ cursor, int2* __restrict__ adj) {
  int e = blockIdx.x * 256 + threadIdx.x;
  if (e >= N_EDGES) return;
  int d = dst[e];
  int pos = atomicAdd(&cursor[d], 1);
  adj[pos] = make_int2(src[e], __float_as_int(ew[e]));
}

// W1 [256][47] -> W1T [47][256] (so GEMM2 loads are contiguous along k)
__global__ __launch_bounds__(256) void transpose_w1(const float* __restrict__ W1,
                                                    float* __restrict__ W1T) {
  int k = threadIdx.x;   // one block of 256
  for (int c = 0; c < 47; ++c) W1T[c * 256 + k] = W1[k * 47 + c];
}

// ---------------- propagation ----------------

__global__ __launch_bounds__(256) void init_kernel(const float4* __restrict__ X,
    float4* __restrict__ xc, float4* __restrict__ prop, int n4) {
  int i = blockIdx.x * 256 + threadIdx.x;
  if (i >= n4) return;
  float4 v = X[i];
  v.x *= 0.5f; v.y *= 0.5f; v.z *= 0.5f; v.w *= 0.5f;
  xc[i] = v;
  prop[i] = v;
}

// gather-sum per dst node: 32 lanes/node, float2/lane, software-pipelined
// batch-of-4 edge prefetch (8 gathers in flight per group).
__global__ __launch_bounds__(256) void spmm_csr(const float2* __restrict__ x,
    const int* __restrict__ row_start, const int2* __restrict__ adj,
    float2* __restrict__ xn, float2* __restrict__ prop) {
  const int node = blockIdx.x * 8 + (threadIdx.x >> 5);   // 100000 % 8 == 0
  const int f2 = threadIdx.x & 31;
  const int beg = row_start[node];
  const int end = row_start[node + 1];
  const int nfull = (end - beg) >> 2;
  float2 a0 = make_float2(0.f, 0.f), a1 = a0;

  int2 e0, e1, e2, e3;
  float2 v0, v1, v2, v3;
  if (nfull > 0) {
    e0 = adj[beg];     e1 = adj[beg + 1]; e2 = adj[beg + 2]; e3 = adj[beg + 3];
    v0 = x[(size_t)e0.x * 32 + f2];
    v1 = x[(size_t)e1.x * 32 + f2];
    v2 = x[(size_t)e2.x * 32 + f2];
    v3 = x[(size_t)e3.x * 32 + f2];
  }
  for (int b = 1; b < nfull; ++b) {
    const int q = beg + 4 * b;
    int2 g0 = adj[q], g1 = adj[q + 1], g2 = adj[q + 2], g3 = adj[q + 3];
    float2 u0 = x[(size_t)g0.x * 32 + f2];
    float2 u1 = x[(size_t)g1.x * 32 + f2];
    float2 u2 = x[(size_t)g2.x * 32 + f2];
    float2 u3 = x[(size_t)g3.x * 32 + f2];
    float w0 = __int_as_float(e0.y), w1 = __int_as_float(e1.y);
    float w2 = __int_as_float(e2.y), w3 = __int_as_float(e3.y);
    a0.x = fmaf(v0.x, w0, a0.x); a0.y = fmaf(v0.y, w0, a0.y);
    a1.x = fmaf(v1.x, w1, a1.x); a1.y = fmaf(v1.y, w1, a1.y);
    a0.x = fmaf(v2.x, w2, a0.x); a0.y = fmaf(v2.y, w2, a0.y);
    a1.x = fmaf(v3.x, w3, a1.x); a1.y = fmaf(v3.y, w3, a1.y);
    e0 = g0; e1 = g1; e2 = g2; e3 = g3;
    v0 = u0; v1 = u1; v2 = u2; v3 = u3;
  }
  if (nfull > 0) {
    float w0 = __int_as_float(e0.y), w1 = __int_as_float(e1.y);
    float w2 = __int_as_float(e2.y), w3 = __int_as_float(e3.y);
    a0.x = fmaf(v0.x, w0, a0.x); a0.y = fmaf(v0.y, w0, a0.y);
    a1.x = fmaf(v1.x, w1, a1.x); a1.y = fmaf(v1.y, w1, a1.y);
    a0.x = fmaf(v2.x, w2, a0.x); a0.y = fmaf(v2.y, w2, a0.y);
    a1.x = fmaf(v3.x, w3, a1.x); a1.y = fmaf(v3.y, w3, a1.y);
  }
  for (int p = beg + 4 * nfull; p < end; ++p) {
    int2 e = adj[p];
    float2 v = x[(size_t)e.x * 32 + f2];
    float w = __int_as_float(e.y);
    a0.x = fmaf(v.x, w, a0.x); a0.y = fmaf(v.y, w, a0.y);
  }
  a0.x += a1.x; a0.y += a1.y;
  const size_t o = (size_t)node * 32 + f2;
  xn[o] = a0;
  float2 pr = prop[o];
  pr.x += a0.x; pr.y += a0.y;
  prop[o] = pr;
}

// ---------------- fused tail, register-blocked, vectorized LDS/VMEM ----------------
// 32 nodes/block. Xp = normalize(prop/9); h = normalize(relu(Xp@W0+b0)); out = h@W1+b1.
__global__ __launch_bounds__(256) void tail_kernel(
    const float* __restrict__ prop, const float* __restrict__ W0,
    const float* __restrict__ b0, const float* __restrict__ W1T,
    const float* __restrict__ b1, float* __restrict__ out) {
  __shared__ __align__(16) float sXTn[32][68];    // [node][k], pad 68
  __shared__ __align__(16) float sHn[32][268];    // [node][k], pad 268 (2-way max on b128)
  __shared__ float sPart[32][33];
  __shared__ float sHinv[32];

  const int t = threadIdx.x;
  const int lane = t & 63;
  const int w = t >> 6;
  const int base = blockIdx.x * 32;   // 3125 * 32 == 100000 exactly

  // ---- load + Xp-normalize: wave handles one node per iter, store node-major ----
  #pragma unroll
  for (int it = 0; it < 8; ++it) {
    const int nb = it * 4 + w;
    float v = prop[(size_t)(base + nb) * NF + lane];
    float ss = v * v;
    #pragma unroll
    for (int m = 1; m < 64; m <<= 1) ss += __shfl_xor(ss, m, 64);
    float nrm = sqrtf(ss) * (1.0f / 9.0f);
    float scale = (1.0f / 9.0f) / (1e-12f + nrm);
    sXTn[nb][lane] = v * scale;
  }
  __syncthreads();

  // ---- GEMM1: thread = 8 cols (8*tc..) x 4 nodes (tn, tn+8, tn+16, tn+24) ----
  const int tc = t >> 3;   // 0..31
  const int tn = t & 7;    // 0..7
  const float4* W0v = (const float4*)W0;
  float4 b0a = ((const float4*)b0)[2 * tc];
  float4 b0b = ((const float4*)b0)[2 * tc + 1];
  float acc[4][8];
  #pragma unroll
  for (int j = 0; j < 4; ++j) {
    acc[j][0] = b0a.x; acc[j][1] = b0a.y; acc[j][2] = b0a.z; acc[j][3] = b0a.w;
    acc[j][4] = b0b.x; acc[j][5] = b0b.y; acc[j][6] = b0b.z; acc[j][7] = b0b.w;
  }
  for (int k = 0; k < NF; k += 4) {
    float xsA[4], xsB[4], xsC[4], xsD[4];
    *(float4*)xsA = *(const float4*)&sXTn[tn][k];
    *(float4*)xsB = *(const float4*)&sXTn[tn + 8][k];
    *(float4*)xsC = *(const float4*)&sXTn[tn + 16][k];
    *(float4*)xsD = *(const float4*)&sXTn[tn + 24][k];
    #pragma unroll
    for (int kk = 0; kk < 4; ++kk) {
      float4 wa = W0v[(k + kk) * 64 + 2 * tc];
      float4 wb = W0v[(k + kk) * 64 + 2 * tc + 1];
      acc[0][0] = fmaf(xsA[kk], wa.x, acc[0][0]);
      acc[0][1] = fmaf(xsA[kk], wa.y, acc[0][1]);
      acc[0][2] = fmaf(xsA[kk], wa.z, acc[0][2]);
      acc[0][3] = fmaf(xsA[kk], wa.w, acc[0][3]);
      acc[0][4] = fmaf(xsA[kk], wb.x, acc[0][4]);
      acc[0][5] = fmaf(xsA[kk], wb.y, acc[0][5]);
      acc[0][6] = fmaf(xsA[kk], wb.z, acc[0][6]);
      acc[0][7] = fmaf(xsA[kk], wb.w, acc[0][7]);
      acc[1][0] = fmaf(xsB[kk], wa.x, acc[1][0]);
      acc[1][1] = fmaf(xsB[kk], wa.y, acc[1][1]);
      acc[1][2] = fmaf(xsB[kk], wa.z, acc[1][2]);
      acc[1][3] = fmaf(xsB[kk], wa.w, acc[1][3]);
      acc[1][4] = fmaf(xsB[kk], wb.x, acc[1][4]);
      acc[1][5] = fmaf(xsB[kk], wb.y, acc[1][5]);
      acc[1][6] = fmaf(xsB[kk], wb.z, acc[1][6]);
      acc[1][7] = fmaf(xsB[kk], wb.w, acc[1][7]);
      acc[2][0] = fmaf(xsC[kk], wa.x, acc[2][0]);
      acc[2][1] = fmaf(xsC[kk], wa.y, acc[2][1]);
      acc[2][2] = fmaf(xsC[kk], wa.z, acc[2][2]);
      acc[2][3] = fmaf(xsC[kk], wa.w, acc[2][3]);
      acc[2][4] = fmaf(xsC[kk], wb.x, acc[2][4]);
      acc[2][5] = fmaf(xsC[kk], wb.y, acc[2][5]);
      acc[2][6] = fmaf(xsC[kk], wb.z, acc[2][6]);
      acc[2][7] = fmaf(xsC[kk], wb.w, acc[2][7]);
      acc[3][0] = fmaf(xsD[kk], wa.x, acc[3][0]);
      acc[3][1] = fmaf(xsD[kk], wa.y, acc[3][1]);
      acc[3][2] = fmaf(xsD[kk], wa.z, acc[3][2]);
      acc[3][3] = fmaf(xsD[kk], wa.w, acc[3][3]);
      acc[3][4] = fmaf(xsD[kk], wb.x, acc[3][4]);
      acc[3][5] = fmaf(xsD[kk], wb.y, acc[3][5]);
      acc[3][6] = fmaf(xsD[kk], wb.z, acc[3][6]);
      acc[3][7] = fmaf(xsD[kk], wb.w, acc[3][7]);
    }
  }

  // relu + per-node partial sumsq
  #pragma unroll
  for (int j = 0; j < 4; ++j) {
    float part = 0.0f;
    #pragma unroll
    for (int i = 0; i < 8; ++i) {
      float a = fmaxf(acc[j][i], 0.0f);
      acc[j][i] = a;
      part = fmaf(a, a, part);
    }
    sPart[tn + 8 * j][tc] = part;
  }
  __syncthreads();

  if (t < 32) {
    float s = 0.0f;
    #pragma unroll
    for (int i = 0; i < 32; ++i) s += sPart[t][i];
    sHinv[t] = 1.0f / (1e-12f + sqrtf(s));
  }
  __syncthreads();

  // scale + store h node-major (vector LDS writes)
  #pragma unroll
  for (int j = 0; j < 4; ++j) {
    float sc = sHinv[tn + 8 * j];
    float4 ha, hb;
    ha.x = acc[j][0] * sc; ha.y = acc[j][1] * sc;
    ha.z = acc[j][2] * sc; ha.w = acc[j][3] * sc;
    hb.x = acc[j][4] * sc; hb.y = acc[j][5] * sc;
    hb.z = acc[j][6] * sc; hb.w = acc[j][7] * sc;
    *(float4*)&sHn[tn + 8 * j][8 * tc] = ha;
    *(float4*)&sHn[tn + 8 * j][8 * tc + 4] = hb;
  }
  __syncthreads();

  // ---- GEMM2: thread = 3 cols {tc2, tc2+16, tc2+32} x 2 nodes {tn2, tn2+16} ----
  const int tn2 = t & 15;
  const int tc2 = t >> 4;   // 0..15
  const bool c3 = (tc2 < 15);
  const float4* w1a = (const float4*)&W1T[tc2 * 256];
  const float4* w1b = (const float4*)&W1T[(tc2 + 16) * 256];
  const float4* w1c = (const float4*)&W1T[(c3 ? tc2 + 32 : tc2) * 256];
  float a00 = b1[tc2], a01 = b1[tc2 + 16], a02 = c3 ? b1[tc2 + 32] : 0.0f;
  float a10 = a00,     a11 = a01,          a12 = a02;
  for (int k4 = 0; k4 < 64; ++k4) {
    float4 h0 = *(const float4*)&sHn[tn2][4 * k4];
    float4 h1 = *(const float4*)&sHn[tn2 + 16][4 * k4];
    float4 wa = w1a[k4];
    float4 wb = w1b[k4];
    float4 wc = w1c[k4];
    a00 = fmaf(h0.x, wa.x, a00); a00 = fmaf(h0.y, wa.y, a00);
    a00 = fmaf(h0.z, wa.z, a00); a00 = fmaf(h0.w, wa.w, a00);
    a01 = fmaf(h0.x, wb.x, a01); a01 = fmaf(h0.y, wb.y, a01);
    a01 = fmaf(h0.z, wb.z, a01); a01 = fmaf(h0.w, wb.w, a01);
    a02 = fmaf(h0.x, wc.x, a02); a02 = fmaf(h0.y, wc.y, a02);
    a02 = fmaf(h0.z, wc.z, a02); a02 = fmaf(h0.w, wc.w, a02);
    a10 = fmaf(h1.x, wa.x, a10); a10 = fmaf(h1.y, wa.y, a10);
    a10 = fmaf(h1.z, wa.z, a10); a10 = fmaf(h1.w, wa.w, a10);
    a11 = fmaf(h1.x, wb.x, a11); a11 = fmaf(h1.y, wb.y, a11);
    a11 = fmaf(h1.z, wb.z, a11); a11 = fmaf(h1.w, wb.w, a11);
    a12 = fmaf(h1.x, wc.x, a12); a12 = fmaf(h1.y, wc.y, a12);
    a12 = fmaf(h1.z, wc.z, a12); a12 = fmaf(h1.w, wc.w, a12);
  }
  {
    const size_t n0 = (size_t)(base + tn2) * 47;
    const size_t n1 = (size_t)(base + tn2 + 16) * 47;
    out[n0 + tc2] = a00;
    out[n0 + tc2 + 16] = a01;
    if (c3) out[n0 + tc2 + 32] = a02;
    out[n1 + tc2] = a10;
    out[n1 + tc2 + 16] = a11;
    if (c3) out[n1 + tc2 + 32] = a12;
  }
}

extern "C" void kernel_launch(void* const* d_in, const int* in_sizes, int n_in,
                              void* d_out, int out_size, void* d_ws, size_t ws_size,
                              hipStream_t stream) {
  (void)in_sizes; (void)n_in; (void)out_size; (void)ws_size;
  const float* X   = (const float*)d_in[0];
  const int*   src = (const int*)d_in[1];
  const int*   dst = (const int*)d_in[2];
  const float* ew  = (const float*)d_in[3];
  const float* W0  = (const float*)d_in[4];
  const float* b0  = (const float*)d_in[5];
  const float* W1  = (const float*)d_in[6];
  const float* b1  = (const float*)d_in[7];
  float* out = (float*)d_out;

  const size_t nf = (size_t)N_NODES * NF;
  float* bufA = (float*)d_ws;
  float* bufB = bufA + nf;
  float* prop = bufB + nf;
  int* counts     = (int*)(prop + nf);
  int* row_start  = counts + N_NODES;            // N_NODES+1
  int* cursor     = row_start + (N_NODES + 1);
  int* blockSums  = cursor + N_NODES;
  int* blockOffs  = blockSums + NBLK;
  float* W1T      = (float*)(((uintptr_t)(blockOffs + NBLK) + 15) & ~(uintptr_t)15);
  int2* adj       = (int2*)(((uintptr_t)(W1T + 47 * 256) + 15) & ~(uintptr_t)15);

  const int eblocks = (N_EDGES + 255) / 256;

  zero_ints<<<NBLK, 256, 0, stream>>>(counts, N_NODES);
  hist_kernel<<<eblocks, 256, 0, stream>>>(dst, counts);
  reduce_counts<<<NBLK, 256, 0, stream>>>(counts, blockSums);
  scan_partials<<<1, 512, 0, stream>>>(blockSums, blockOffs);
  scan_blocks<<<NBLK, 256, 0, stream>>>(counts, blockOffs, row_start, cursor);
  fill_kernel<<<eblocks, 256, 0, stream>>>(src, dst, ew, cursor, adj);
  transpose_w1<<<1, 256, 0, stream>>>(W1, W1T);

  const int n4 = (int)(nf / 4);
  init_kernel<<<(n4 + 255) / 256, 256, 0, stream>>>(
      (const float4*)X, (float4*)bufA, (float4*)prop, n4);

  float* xc = bufA;
  float* xn = bufB;
  for (int r = 0; r < ORDER; ++r) {
    spmm_csr<<<N_NODES / 8, 256, 0, stream>>>(
        (const float2*)xc, row_start, adj, (float2*)xn, (float2*)prop);
    float* tmp = xc; xc = xn; xn = tmp;
  }

  tail_kernel<<<N_NODES / 32, 256, 0, stream>>>(prop, W0, b0, W1T, b1, out);
}